// Round 3
// baseline (640.670 us; speedup 1.0000x reference)
//
#include <hip/hip_runtime.h>
#include <hip/hip_bf16.h>

// BitNet 4-layer MLP forward, MI355X — round 3: 256^2 8-phase i8 GEMM (T2+T3+T4+T5+T1)
// for the two big H x H layers; proven 128^2 2-phase i8 GEMM kept for L1/L4.

typedef __attribute__((ext_vector_type(4))) int i32x4_t;

#define GLDS16(g, l) __builtin_amdgcn_global_load_lds( \
    (const __attribute__((address_space(1))) unsigned int*)(g), \
    (__attribute__((address_space(3))) unsigned int*)(l), 16, 0, 0)

static __device__ __forceinline__ unsigned char f2i8(float f) {
  return (unsigned char)(int)f;   // f already rint'ed and clipped
}

// ---------------- weight abs-mean (deterministic two-stage fp64) ------------
__global__ __launch_bounds__(256) void absmean_part_k(
    const float* __restrict__ W, int n4, double* __restrict__ part)
{
  double s = 0.0;
  const int stride = gridDim.x * 256;
  for (int i = blockIdx.x * 256 + threadIdx.x; i < n4; i += stride) {
    float4 v = ((const float4*)W)[i];
    s += (double)fabsf(v.x); s += (double)fabsf(v.y);
    s += (double)fabsf(v.z); s += (double)fabsf(v.w);
  }
  __shared__ double sd[256];
  sd[threadIdx.x] = s;
  __syncthreads();
  for (int st = 128; st > 0; st >>= 1) {
    if (threadIdx.x < st) sd[threadIdx.x] += sd[threadIdx.x + st];
    __syncthreads();
  }
  if (threadIdx.x == 0) part[blockIdx.x] = sd[0];
}

__global__ __launch_bounds__(256) void absmean_fin_k(
    const double* __restrict__ part, int nPart, double n,
    float* __restrict__ wsc, int widx)
{
  __shared__ double sd[256];
  double s = 0.0;
  for (int i = threadIdx.x; i < nPart; i += 256) s += part[i];
  sd[threadIdx.x] = s;
  __syncthreads();
  for (int st = 128; st > 0; st >>= 1) {
    if (threadIdx.x < st) sd[threadIdx.x] += sd[threadIdx.x + st];
    __syncthreads();
  }
  if (threadIdx.x == 0) {
    float mean = (float)(sd[0] / n);
    float scale = 1.f / fmaxf(mean, 1e-5f);
    wsc[widx * 2]     = scale;
    wsc[widx * 2 + 1] = 1.f / scale;
  }
}

// ---------------- weight ternary quantization to i8 {-1,0,1} ----------------
__global__ __launch_bounds__(256) void quant_w_k(
    const float* __restrict__ W, unsigned int* __restrict__ Wq,
    const float* __restrict__ wsc, int widx, int n4)
{
  const float s = wsc[widx * 2];
  const int stride = gridDim.x * 256;
  for (int i = blockIdx.x * 256 + threadIdx.x; i < n4; i += stride) {
    float4 v = ((const float4*)W)[i];
    unsigned int u =
        (unsigned int)f2i8(fminf(fmaxf(rintf(v.x * s), -1.f), 1.f)) |
        ((unsigned int)f2i8(fminf(fmaxf(rintf(v.y * s), -1.f), 1.f)) << 8) |
        ((unsigned int)f2i8(fminf(fmaxf(rintf(v.z * s), -1.f), 1.f)) << 16) |
        ((unsigned int)f2i8(fminf(fmaxf(rintf(v.w * s), -1.f), 1.f)) << 24);
    Wq[i] = u;
  }
}

// ---------------- per-row activation quantization to i8 ---------------------
template<int D>
__global__ __launch_bounds__(256) void act_quant_k(
    const float* __restrict__ X, unsigned int* __restrict__ Xq,
    float* __restrict__ inv_sa)
{
  constexpr int PER = D / 1024;
  const int row = blockIdx.x, tid = threadIdx.x;
  const float4* xr = (const float4*)(X + (size_t)row * D);
  float4 v[PER];
  float m = 0.f;
  #pragma unroll
  for (int i = 0; i < PER; ++i) {
    v[i] = xr[tid + 256 * i];
    m = fmaxf(m, fmaxf(fmaxf(fabsf(v[i].x), fabsf(v[i].y)),
                       fmaxf(fabsf(v[i].z), fabsf(v[i].w))));
  }
  #pragma unroll
  for (int off = 32; off >= 1; off >>= 1) m = fmaxf(m, __shfl_xor(m, off));
  __shared__ float wm[4];
  if ((tid & 63) == 0) wm[tid >> 6] = m;
  __syncthreads();
  m = fmaxf(fmaxf(wm[0], wm[1]), fmaxf(wm[2], wm[3]));
  const float s = 127.f / fmaxf(m, 1e-5f);
  if (tid == 0) inv_sa[row] = 1.f / s;
  unsigned int* oq = Xq + (size_t)row * (D / 4);
  #pragma unroll
  for (int i = 0; i < PER; ++i) {
    unsigned int u =
        (unsigned int)f2i8(fminf(fmaxf(rintf(v[i].x * s), -128.f), 127.f)) |
        ((unsigned int)f2i8(fminf(fmaxf(rintf(v[i].y * s), -128.f), 127.f)) << 8) |
        ((unsigned int)f2i8(fminf(fmaxf(rintf(v[i].z * s), -128.f), 127.f)) << 16) |
        ((unsigned int)f2i8(fminf(fmaxf(rintf(v[i].w * s), -128.f), 127.f)) << 24);
    oq[tid + 256 * i] = u;
  }
}

// ---------------- 128^2 2-phase i8 GEMM (proven; used for L1/L4) ------------
template<int K, int N, bool TANH>
__global__ __launch_bounds__(256) void gemm_bt(
    const signed char* __restrict__ A, const signed char* __restrict__ W,
    const float* __restrict__ inv_sa, const float* __restrict__ wsc, int widx,
    const float* __restrict__ bias, float* __restrict__ out)
{
  __shared__ __align__(16) signed char As[128 * 64];
  __shared__ __align__(16) signed char Bs[128 * 64];
  const int tid = threadIdx.x;
  const int wv = tid >> 6, ln = tid & 63;
  const int bm = blockIdx.y, bn = blockIdx.x;
  const int wr = wv >> 1, wc = wv & 1;
  const signed char* Ab = A + (size_t)bm * 128 * K;
  const signed char* Wb = W + (size_t)bn * 128 * K;
  i32x4_t acc[4][4];
  #pragma unroll
  for (int m = 0; m < 4; ++m)
    #pragma unroll
    for (int n = 0; n < 4; ++n) acc[m][n] = (i32x4_t){0, 0, 0, 0};

  for (int k0 = 0; k0 < K; k0 += 64) {
    #pragma unroll
    for (int l = 0; l < 2; ++l) {
      const int c = l * 256 + wv * 64 + ln;
      const int row = c >> 2;
      const int kc = (c & 3) * 16;
      GLDS16(Ab + (size_t)row * K + k0 + kc, As + (l * 256 + wv * 64) * 16);
      GLDS16(Wb + (size_t)row * K + k0 + kc, Bs + (l * 256 + wv * 64) * 16);
    }
    __syncthreads();
    i32x4_t aw[4], bw[4];
    #pragma unroll
    for (int m = 0; m < 4; ++m)
      aw[m] = *(const i32x4_t*)(As + (wr * 64 + m * 16 + (ln & 15)) * 64 + (ln >> 4) * 16);
    #pragma unroll
    for (int n = 0; n < 4; ++n)
      bw[n] = *(const i32x4_t*)(Bs + (wc * 64 + n * 16 + (ln & 15)) * 64 + (ln >> 4) * 16);
    #pragma unroll
    for (int m = 0; m < 4; ++m)
      #pragma unroll
      for (int n = 0; n < 4; ++n)
        acc[m][n] = __builtin_amdgcn_mfma_i32_16x16x64_i8(aw[m], bw[n], acc[m][n], 0, 0, 0);
    __syncthreads();
  }

  const float invw = wsc[widx * 2 + 1];
  #pragma unroll
  for (int m = 0; m < 4; ++m) {
    const int gb0 = bm * 128 + wr * 64 + m * 16 + ((ln >> 4) << 2);
    #pragma unroll
    for (int r = 0; r < 4; ++r) {
      const int gb = gb0 + r;
      const float fa = inv_sa[gb] * invw;
      #pragma unroll
      for (int n = 0; n < 4; ++n) {
        const int go = bn * 128 + wc * 64 + n * 16 + (ln & 15);
        const float v = (float)acc[m][n][r] * fa + bias[go];
        out[(size_t)gb * N + go] = TANH ? tanhf(v) : v;
      }
    }
  }
}

// ---------------- 256^2 8-phase i8 GEMM (T1+T2+T3+T4+T5) --------------------
// BM=BN=256, BK=128 i8 (128B rows — byte-identical to the verified bf16 BK=64
// template). 8 waves (2M x 4N), per-wave output 128x64. LDS 128KB:
// buf{0,1} x { A[2 halves x 16KB], B[2 halves x 16KB] }. st_16x32 XOR swizzle
// applied via pre-swizzled global source (write) + swizzled ds_read (read).
// Per K-tile t (4 phases): stage [B1(t+1), B0(t+2), A0(t+2), A1(t+2)];
// vmcnt(6) once per K-tile (3 half-tiles in flight); never 0 until tail.
template<int K, int N, bool TANH>
__global__ __launch_bounds__(512, 2) void gemm8p(
    const signed char* __restrict__ A, const signed char* __restrict__ W,
    const float* __restrict__ inv_sa, const float* __restrict__ wsc, int widx,
    const float* __restrict__ bias, float* __restrict__ out)
{
  __shared__ __align__(16) signed char lds[131072];
  constexpr int NT = K / 128;
  const int tid = threadIdx.x;
  const int wv = tid >> 6, ln = tid & 63;
  const int wr = wv >> 2, wc = wv & 3;          // 2 x 4 wave grid
  const int g = ln >> 4, rl = ln & 15;
  const int kswz = (g * 16) ^ (((rl >> 2) & 1) << 5);   // read-side st_16x32

  // XCD-aware block swizzle (nwg % 8 == 0 for all our grids)
  const int nwg = gridDim.x * gridDim.y;
  int lbid = blockIdx.y * gridDim.x + blockIdx.x;
  lbid = (lbid & 7) * (nwg >> 3) + (lbid >> 3);
  const int bn = lbid % gridDim.x, bm = lbid / gridDim.x;

  const signed char* Abase = A + (size_t)bm * 256 * K;
  const signed char* Wbase = W + (size_t)bn * 256 * K;

  // staging: 2 x 16B chunks per thread per 16KB half-tile; pre-swizzled source
  const int c0 = tid, c1 = 512 + tid;
  const int c0p = c0 ^ (((c0 >> 5) & 1) << 1);
  const int c1p = c1 ^ (((c1 >> 5) & 1) << 1);
  const int r0 = c0p >> 3, k0c = (c0p & 7) * 16;
  const int r1 = c1p >> 3, k1c = (c1p & 7) * 16;

  auto stageA = [&](int tt, int h) {
    if (tt >= NT) return;
    signed char* d = lds + ((tt & 1) << 16) + h * 16384;
    const signed char* gsrc = Abase + (size_t)(h * 128) * K + (size_t)tt * 128;
    GLDS16(gsrc + (size_t)r0 * K + k0c, d + (c0 << 4));
    GLDS16(gsrc + (size_t)r1 * K + k1c, d + (c1 << 4));
  };
  auto stageB = [&](int tt, int h) {
    if (tt >= NT) return;
    signed char* d = lds + ((tt & 1) << 16) + 32768 + h * 16384;
    const signed char* gsrc = Wbase + (size_t)(h * 128) * K + (size_t)tt * 128;
    GLDS16(gsrc + (size_t)r0 * K + k0c, d + (c0 << 4));
    GLDS16(gsrc + (size_t)r1 * K + k1c, d + (c1 << 4));
  };

  i32x4_t acc[8][4];
  #pragma unroll
  for (int m = 0; m < 8; ++m)
    #pragma unroll
    for (int n = 0; n < 4; ++n) acc[m][n] = (i32x4_t){0, 0, 0, 0};

  i32x4_t bf[4][2];
  auto quad = [&](int q, i32x4_t (*fa)[2]) {
    #pragma unroll
    for (int mm = 0; mm < 2; ++mm)
      #pragma unroll
      for (int n = 0; n < 4; ++n)
        #pragma unroll
        for (int ks = 0; ks < 2; ++ks)
          acc[q * 2 + mm][n] = __builtin_amdgcn_mfma_i32_16x16x64_i8(
              fa[mm][ks], bf[n][ks], acc[q * 2 + mm][n], 0, 0, 0);
  };

  // prologue: K-tile 0 fully + 3 halves of K-tile 1
  stageA(0, 0); stageA(0, 1); stageB(0, 0); stageB(0, 1);
  stageB(1, 0); stageA(1, 0); stageA(1, 1);
  if (NT > 1) asm volatile("s_waitcnt vmcnt(6)" ::: "memory");
  else        asm volatile("s_waitcnt vmcnt(0)" ::: "memory");
  __builtin_amdgcn_s_barrier();

  for (int t = 0; t < NT; ++t) {
    signed char* myA = lds + ((t & 1) << 16) + wr * 16384;
    signed char* myB = lds + ((t & 1) << 16) + 32768 + (wc >> 1) * 16384
                       + ((wc & 1) * 64) * 128;
    i32x4_t a01[2][2], a27[6][2];

    // -------- P1: read A m0-1 + all B; stage B1(t+1) --------
    #pragma unroll
    for (int mm = 0; mm < 2; ++mm)
      #pragma unroll
      for (int ks = 0; ks < 2; ++ks)
        a01[mm][ks] = *(const i32x4_t*)(myA + (mm * 16 + rl) * 128 + ks * 64 + kswz);
    #pragma unroll
    for (int n = 0; n < 4; ++n)
      #pragma unroll
      for (int ks = 0; ks < 2; ++ks)
        bf[n][ks] = *(const i32x4_t*)(myB + (n * 16 + rl) * 128 + ks * 64 + kswz);
    stageB(t + 1, 1);
    asm volatile("s_waitcnt lgkmcnt(8)" ::: "memory");
    __builtin_amdgcn_s_barrier();
    asm volatile("s_waitcnt lgkmcnt(0)" ::: "memory");
    __builtin_amdgcn_sched_barrier(0);
    __builtin_amdgcn_s_setprio(1);
    quad(0, a01);
    __builtin_amdgcn_s_setprio(0);
    __builtin_amdgcn_s_barrier();

    // -------- P2: read A m2-7; stage B0(t+2) --------
    #pragma unroll
    for (int mm = 0; mm < 6; ++mm)
      #pragma unroll
      for (int ks = 0; ks < 2; ++ks)
        a27[mm][ks] = *(const i32x4_t*)(myA + ((mm + 2) * 16 + rl) * 128 + ks * 64 + kswz);
    stageB(t + 2, 0);
    asm volatile("s_waitcnt lgkmcnt(8)" ::: "memory");
    __builtin_amdgcn_s_barrier();
    asm volatile("s_waitcnt lgkmcnt(0)" ::: "memory");
    __builtin_amdgcn_sched_barrier(0);
    __builtin_amdgcn_s_setprio(1);
    quad(1, &a27[0]);
    __builtin_amdgcn_s_setprio(0);
    __builtin_amdgcn_s_barrier();

    // -------- P3: stage A0(t+2) --------
    stageA(t + 2, 0);
    __builtin_amdgcn_s_barrier();
    __builtin_amdgcn_s_setprio(1);
    quad(2, &a27[2]);
    __builtin_amdgcn_s_setprio(0);
    __builtin_amdgcn_s_barrier();

    // -------- P4: stage A1(t+2); counted vmcnt --------
    stageA(t + 2, 1);
    if (t < NT - 2) asm volatile("s_waitcnt vmcnt(6)" ::: "memory");
    else            asm volatile("s_waitcnt vmcnt(0)" ::: "memory");
    __builtin_amdgcn_s_barrier();
    __builtin_amdgcn_s_setprio(1);
    quad(3, &a27[4]);
    __builtin_amdgcn_s_setprio(0);
    __builtin_amdgcn_s_barrier();
  }

  // -------- epilogue --------
  const float invw = wsc[widx * 2 + 1];
  const int row0 = bm * 256 + wr * 128;
  const int col0 = bn * 256 + wc * 64;
  #pragma unroll
  for (int m = 0; m < 8; ++m) {
    #pragma unroll
    for (int r = 0; r < 4; ++r) {
      const int gb = row0 + m * 16 + g * 4 + r;
      const float fa = inv_sa[gb] * invw;
      #pragma unroll
      for (int n = 0; n < 4; ++n) {
        const int go = col0 + n * 16 + rl;
        const float v = (float)acc[m][n][r] * fa + bias[go];
        out[(size_t)gb * N + go] = TANH ? tanhf(v) : v;
      }
    }
  }
}

// ---------------- driver ----------------------------------------------------
extern "C" void kernel_launch(void* const* d_in, const int* in_sizes, int n_in,
                              void* d_out, int out_size, void* d_ws, size_t ws_size,
                              hipStream_t stream)
{
  const float* x  = (const float*)d_in[0];
  const float* w1 = (const float*)d_in[1]; const float* b1 = (const float*)d_in[2];
  const float* w2 = (const float*)d_in[3]; const float* b2 = (const float*)d_in[4];
  const float* w3 = (const float*)d_in[5]; const float* b3 = (const float*)d_in[6];
  const float* w4 = (const float*)d_in[7]; const float* b4 = (const float*)d_in[8];
  float* out = (float*)d_out;

  constexpr int B = 8192, DIN = 1024, H = 4096, DOUT = 1024;
  char* ws = (char*)d_ws;
  size_t off = 0;
  float*       hbuf = (float*)(ws + off);        off += (size_t)B * H * 4;
  signed char* xq   = (signed char*)(ws + off);  off += (size_t)B * H;
  signed char* wq   = (signed char*)(ws + off);  off += (size_t)H * H;
  float*       inv_sa = (float*)(ws + off);      off += (size_t)B * 4;
  double*      part = (double*)(ws + off);       off += 1024 * 8;
  float*       wsc  = (float*)(ws + off);        off += 64;

  absmean_part_k<<<1024, 256, 0, stream>>>(w1, H * DIN / 4, part);
  absmean_fin_k<<<1, 256, 0, stream>>>(part, 1024, (double)H * DIN, wsc, 0);
  absmean_part_k<<<1024, 256, 0, stream>>>(w2, H * H / 4, part);
  absmean_fin_k<<<1, 256, 0, stream>>>(part, 1024, (double)H * H, wsc, 1);
  absmean_part_k<<<1024, 256, 0, stream>>>(w3, H * H / 4, part);
  absmean_fin_k<<<1, 256, 0, stream>>>(part, 1024, (double)H * H, wsc, 2);
  absmean_part_k<<<1024, 256, 0, stream>>>(w4, DOUT * H / 4, part);
  absmean_fin_k<<<1, 256, 0, stream>>>(part, 1024, (double)DOUT * H, wsc, 3);

  // layer 1 (K=1024): 128^2 kernel, full-chip grid
  act_quant_k<DIN><<<B, 256, 0, stream>>>(x, (unsigned int*)xq, inv_sa);
  quant_w_k<<<2048, 256, 0, stream>>>(w1, (unsigned int*)wq, wsc, 0, H * DIN / 4);
  gemm_bt<DIN, H, true><<<dim3(H / 128, B / 128), 256, 0, stream>>>(
      xq, wq, inv_sa, wsc, 0, b1, hbuf);

  // layer 2 (4096^2 x 8192): 256^2 8-phase
  act_quant_k<H><<<B, 256, 0, stream>>>(hbuf, (unsigned int*)xq, inv_sa);
  quant_w_k<<<2048, 256, 0, stream>>>(w2, (unsigned int*)wq, wsc, 1, H * H / 4);
  gemm8p<H, H, true><<<dim3(H / 256, B / 256), 512, 0, stream>>>(
      xq, wq, inv_sa, wsc, 1, b2, hbuf);

  // layer 3
  act_quant_k<H><<<B, 256, 0, stream>>>(hbuf, (unsigned int*)xq, inv_sa);
  quant_w_k<<<2048, 256, 0, stream>>>(w3, (unsigned int*)wq, wsc, 2, H * H / 4);
  gemm8p<H, H, true><<<dim3(H / 256, B / 256), 512, 0, stream>>>(
      xq, wq, inv_sa, wsc, 2, b3, hbuf);

  // layer 4 (N=1024): 128^2 kernel
  act_quant_k<H><<<B, 256, 0, stream>>>(hbuf, (unsigned int*)xq, inv_sa);
  quant_w_k<<<2048, 256, 0, stream>>>(w4, (unsigned int*)wq, wsc, 3, DOUT * H / 4);
  gemm_bt<H, DOUT, false><<<dim3(DOUT / 128, B / 128), 256, 0, stream>>>(
      xq, wq, inv_sa, wsc, 3, b4, out);
}

// Round 4
// 619.957 us; speedup vs baseline: 1.0334x; 1.0334x over previous
//
#include <hip/hip_runtime.h>
#include <hip/hip_bf16.h>

// BitNet 4-layer MLP forward, MI355X — round 4: fix gemm8p LDS swizzle.
// Read pattern addr=row*128+ks*64+g*16 needs the 3-bit XOR swizzle
// (col ^= (row&7)<<4) to spread 16 same-g lanes over all 8 16B slots
// (2 lanes/bank = free). Round 3's one-bit st_16x32 only halved conflicts.

typedef __attribute__((ext_vector_type(4))) int i32x4_t;

#define GLDS16(g, l) __builtin_amdgcn_global_load_lds( \
    (const __attribute__((address_space(1))) unsigned int*)(g), \
    (__attribute__((address_space(3))) unsigned int*)(l), 16, 0, 0)

static __device__ __forceinline__ unsigned char f2i8(float f) {
  return (unsigned char)(int)f;   // f already rint'ed and clipped
}

// ---------------- weight abs-mean (deterministic two-stage fp64) ------------
__global__ __launch_bounds__(256) void absmean_part_k(
    const float* __restrict__ W, int n4, double* __restrict__ part)
{
  double s = 0.0;
  const int stride = gridDim.x * 256;
  for (int i = blockIdx.x * 256 + threadIdx.x; i < n4; i += stride) {
    float4 v = ((const float4*)W)[i];
    s += (double)fabsf(v.x); s += (double)fabsf(v.y);
    s += (double)fabsf(v.z); s += (double)fabsf(v.w);
  }
  __shared__ double sd[256];
  sd[threadIdx.x] = s;
  __syncthreads();
  for (int st = 128; st > 0; st >>= 1) {
    if (threadIdx.x < st) sd[threadIdx.x] += sd[threadIdx.x + st];
    __syncthreads();
  }
  if (threadIdx.x == 0) part[blockIdx.x] = sd[0];
}

__global__ __launch_bounds__(256) void absmean_fin_k(
    const double* __restrict__ part, int nPart, double n,
    float* __restrict__ wsc, int widx)
{
  __shared__ double sd[256];
  double s = 0.0;
  for (int i = threadIdx.x; i < nPart; i += 256) s += part[i];
  sd[threadIdx.x] = s;
  __syncthreads();
  for (int st = 128; st > 0; st >>= 1) {
    if (threadIdx.x < st) sd[threadIdx.x] += sd[threadIdx.x + st];
    __syncthreads();
  }
  if (threadIdx.x == 0) {
    float mean = (float)(sd[0] / n);
    float scale = 1.f / fmaxf(mean, 1e-5f);
    wsc[widx * 2]     = scale;
    wsc[widx * 2 + 1] = 1.f / scale;
  }
}

// ---------------- weight ternary quantization to i8 {-1,0,1} ----------------
__global__ __launch_bounds__(256) void quant_w_k(
    const float* __restrict__ W, unsigned int* __restrict__ Wq,
    const float* __restrict__ wsc, int widx, int n4)
{
  const float s = wsc[widx * 2];
  const int stride = gridDim.x * 256;
  for (int i = blockIdx.x * 256 + threadIdx.x; i < n4; i += stride) {
    float4 v = ((const float4*)W)[i];
    unsigned int u =
        (unsigned int)f2i8(fminf(fmaxf(rintf(v.x * s), -1.f), 1.f)) |
        ((unsigned int)f2i8(fminf(fmaxf(rintf(v.y * s), -1.f), 1.f)) << 8) |
        ((unsigned int)f2i8(fminf(fmaxf(rintf(v.z * s), -1.f), 1.f)) << 16) |
        ((unsigned int)f2i8(fminf(fmaxf(rintf(v.w * s), -1.f), 1.f)) << 24);
    Wq[i] = u;
  }
}

// ---------------- per-row activation quantization to i8 ---------------------
template<int D>
__global__ __launch_bounds__(256) void act_quant_k(
    const float* __restrict__ X, unsigned int* __restrict__ Xq,
    float* __restrict__ inv_sa)
{
  constexpr int PER = D / 1024;
  const int row = blockIdx.x, tid = threadIdx.x;
  const float4* xr = (const float4*)(X + (size_t)row * D);
  float4 v[PER];
  float m = 0.f;
  #pragma unroll
  for (int i = 0; i < PER; ++i) {
    v[i] = xr[tid + 256 * i];
    m = fmaxf(m, fmaxf(fmaxf(fabsf(v[i].x), fabsf(v[i].y)),
                       fmaxf(fabsf(v[i].z), fabsf(v[i].w))));
  }
  #pragma unroll
  for (int off = 32; off >= 1; off >>= 1) m = fmaxf(m, __shfl_xor(m, off));
  __shared__ float wm[4];
  if ((tid & 63) == 0) wm[tid >> 6] = m;
  __syncthreads();
  m = fmaxf(fmaxf(wm[0], wm[1]), fmaxf(wm[2], wm[3]));
  const float s = 127.f / fmaxf(m, 1e-5f);
  if (tid == 0) inv_sa[row] = 1.f / s;
  unsigned int* oq = Xq + (size_t)row * (D / 4);
  #pragma unroll
  for (int i = 0; i < PER; ++i) {
    unsigned int u =
        (unsigned int)f2i8(fminf(fmaxf(rintf(v[i].x * s), -128.f), 127.f)) |
        ((unsigned int)f2i8(fminf(fmaxf(rintf(v[i].y * s), -128.f), 127.f)) << 8) |
        ((unsigned int)f2i8(fminf(fmaxf(rintf(v[i].z * s), -128.f), 127.f)) << 16) |
        ((unsigned int)f2i8(fminf(fmaxf(rintf(v[i].w * s), -128.f), 127.f)) << 24);
    oq[tid + 256 * i] = u;
  }
}

// ---------------- 128^2 2-phase i8 GEMM (proven; used for L1/L4) ------------
template<int K, int N, bool TANH>
__global__ __launch_bounds__(256) void gemm_bt(
    const signed char* __restrict__ A, const signed char* __restrict__ W,
    const float* __restrict__ inv_sa, const float* __restrict__ wsc, int widx,
    const float* __restrict__ bias, float* __restrict__ out)
{
  __shared__ __align__(16) signed char As[128 * 64];
  __shared__ __align__(16) signed char Bs[128 * 64];
  const int tid = threadIdx.x;
  const int wv = tid >> 6, ln = tid & 63;
  const int bm = blockIdx.y, bn = blockIdx.x;
  const int wr = wv >> 1, wc = wv & 1;
  const signed char* Ab = A + (size_t)bm * 128 * K;
  const signed char* Wb = W + (size_t)bn * 128 * K;
  i32x4_t acc[4][4];
  #pragma unroll
  for (int m = 0; m < 4; ++m)
    #pragma unroll
    for (int n = 0; n < 4; ++n) acc[m][n] = (i32x4_t){0, 0, 0, 0};

  for (int k0 = 0; k0 < K; k0 += 64) {
    #pragma unroll
    for (int l = 0; l < 2; ++l) {
      const int c = l * 256 + wv * 64 + ln;
      const int row = c >> 2;
      const int kc = (c & 3) * 16;
      GLDS16(Ab + (size_t)row * K + k0 + kc, As + (l * 256 + wv * 64) * 16);
      GLDS16(Wb + (size_t)row * K + k0 + kc, Bs + (l * 256 + wv * 64) * 16);
    }
    __syncthreads();
    i32x4_t aw[4], bw[4];
    #pragma unroll
    for (int m = 0; m < 4; ++m)
      aw[m] = *(const i32x4_t*)(As + (wr * 64 + m * 16 + (ln & 15)) * 64 + (ln >> 4) * 16);
    #pragma unroll
    for (int n = 0; n < 4; ++n)
      bw[n] = *(const i32x4_t*)(Bs + (wc * 64 + n * 16 + (ln & 15)) * 64 + (ln >> 4) * 16);
    #pragma unroll
    for (int m = 0; m < 4; ++m)
      #pragma unroll
      for (int n = 0; n < 4; ++n)
        acc[m][n] = __builtin_amdgcn_mfma_i32_16x16x64_i8(aw[m], bw[n], acc[m][n], 0, 0, 0);
    __syncthreads();
  }

  const float invw = wsc[widx * 2 + 1];
  #pragma unroll
  for (int m = 0; m < 4; ++m) {
    const int gb0 = bm * 128 + wr * 64 + m * 16 + ((ln >> 4) << 2);
    #pragma unroll
    for (int r = 0; r < 4; ++r) {
      const int gb = gb0 + r;
      const float fa = inv_sa[gb] * invw;
      #pragma unroll
      for (int n = 0; n < 4; ++n) {
        const int go = bn * 128 + wc * 64 + n * 16 + (ln & 15);
        const float v = (float)acc[m][n][r] * fa + bias[go];
        out[(size_t)gb * N + go] = TANH ? tanhf(v) : v;
      }
    }
  }
}

// ---------------- 256^2 8-phase i8 GEMM (T1+T2(3-bit)+T3+T4+T5) -------------
// BM=BN=256, BK=128 i8. 8 waves (2M x 4N), per-wave output 128x64.
// LDS 128KB: buf{0,1} x { A[2x16KB], B[2x16KB] }.
// Swizzle: LDS[addr] = G[addr ^ ((addr>>7 & 7)<<4)] — write via pre-swizzled
// global source (LDS dest linear, rule #21), read via col ^= (row&7)<<4.
// Per K-tile t (4 phases): stage [B1(t+1), B0(t+2), A0(t+2), A1(t+2)];
// vmcnt(6) once per K-tile; never 0 until tail.
template<int K, int N, bool TANH>
__global__ __launch_bounds__(512, 2) void gemm8p(
    const signed char* __restrict__ A, const signed char* __restrict__ W,
    const float* __restrict__ inv_sa, const float* __restrict__ wsc, int widx,
    const float* __restrict__ bias, float* __restrict__ out)
{
  __shared__ __align__(16) signed char lds[131072];
  constexpr int NT = K / 128;
  const int tid = threadIdx.x;
  const int wv = tid >> 6, ln = tid & 63;
  const int wr = wv >> 2, wc = wv & 3;          // 2 x 4 wave grid
  const int g = ln >> 4, rl = ln & 15;
  const int colswz = (rl & 7) << 4;             // read-side 3-bit XOR

  // XCD-aware block swizzle (nwg % 8 == 0 for all our grids)
  const int nwg = gridDim.x * gridDim.y;
  int lbid = blockIdx.y * gridDim.x + blockIdx.x;
  lbid = (lbid & 7) * (nwg >> 3) + (lbid >> 3);
  const int bn = lbid % gridDim.x, bm = lbid / gridDim.x;

  const signed char* Abase = A + (size_t)bm * 256 * K;
  const signed char* Wbase = W + (size_t)bn * 256 * K;

  // staging: 2 x 16B chunks per thread per 16KB half-tile.
  // LDS chunk c (linear dest) sources global chunk c ^ ((c>>3)&7):
  // row unchanged, 16B column slot permuted within the 128B row.
  const int c0 = tid, c1 = 512 + tid;
  const int r0 = c0 >> 3, k0c = ((c0 ^ (c0 >> 3)) & 7) * 16;
  const int r1 = c1 >> 3, k1c = ((c1 ^ (c1 >> 3)) & 7) * 16;

  auto stageA = [&](int tt, int h) {
    if (tt >= NT) return;
    signed char* d = lds + ((tt & 1) << 16) + h * 16384;
    const signed char* gsrc = Abase + (size_t)(h * 128) * K + (size_t)tt * 128;
    GLDS16(gsrc + (size_t)r0 * K + k0c, d + (c0 << 4));
    GLDS16(gsrc + (size_t)r1 * K + k1c, d + (c1 << 4));
  };
  auto stageB = [&](int tt, int h) {
    if (tt >= NT) return;
    signed char* d = lds + ((tt & 1) << 16) + 32768 + h * 16384;
    const signed char* gsrc = Wbase + (size_t)(h * 128) * K + (size_t)tt * 128;
    GLDS16(gsrc + (size_t)r0 * K + k0c, d + (c0 << 4));
    GLDS16(gsrc + (size_t)r1 * K + k1c, d + (c1 << 4));
  };

  i32x4_t acc[8][4];
  #pragma unroll
  for (int m = 0; m < 8; ++m)
    #pragma unroll
    for (int n = 0; n < 4; ++n) acc[m][n] = (i32x4_t){0, 0, 0, 0};

  i32x4_t bf[4][2];
  auto quad = [&](int q, i32x4_t (*fa)[2]) {
    #pragma unroll
    for (int mm = 0; mm < 2; ++mm)
      #pragma unroll
      for (int n = 0; n < 4; ++n)
        #pragma unroll
        for (int ks = 0; ks < 2; ++ks)
          acc[q * 2 + mm][n] = __builtin_amdgcn_mfma_i32_16x16x64_i8(
              fa[mm][ks], bf[n][ks], acc[q * 2 + mm][n], 0, 0, 0);
  };

  // prologue: K-tile 0 fully + 3 halves of K-tile 1
  stageA(0, 0); stageA(0, 1); stageB(0, 0); stageB(0, 1);
  stageB(1, 0); stageA(1, 0); stageA(1, 1);
  if (NT > 1) asm volatile("s_waitcnt vmcnt(6)" ::: "memory");
  else        asm volatile("s_waitcnt vmcnt(0)" ::: "memory");
  __builtin_amdgcn_s_barrier();

  for (int t = 0; t < NT; ++t) {
    signed char* myA = lds + ((t & 1) << 16) + wr * 16384;
    signed char* myB = lds + ((t & 1) << 16) + 32768 + (wc >> 1) * 16384
                       + ((wc & 1) * 64) * 128;
    i32x4_t a01[2][2], a27[6][2];

    // -------- P1: read A m0-1 + all B; stage B1(t+1) --------
    #pragma unroll
    for (int mm = 0; mm < 2; ++mm)
      #pragma unroll
      for (int ks = 0; ks < 2; ++ks)
        a01[mm][ks] = *(const i32x4_t*)(myA + (mm * 16 + rl) * 128
                                        + ((ks * 64 + g * 16) ^ colswz));
    #pragma unroll
    for (int n = 0; n < 4; ++n)
      #pragma unroll
      for (int ks = 0; ks < 2; ++ks)
        bf[n][ks] = *(const i32x4_t*)(myB + (n * 16 + rl) * 128
                                      + ((ks * 64 + g * 16) ^ colswz));
    stageB(t + 1, 1);
    asm volatile("s_waitcnt lgkmcnt(8)" ::: "memory");
    __builtin_amdgcn_s_barrier();
    asm volatile("s_waitcnt lgkmcnt(0)" ::: "memory");
    __builtin_amdgcn_sched_barrier(0);
    __builtin_amdgcn_s_setprio(1);
    quad(0, a01);
    __builtin_amdgcn_s_setprio(0);
    __builtin_amdgcn_s_barrier();

    // -------- P2: read A m2-7; stage B0(t+2) --------
    #pragma unroll
    for (int mm = 0; mm < 6; ++mm)
      #pragma unroll
      for (int ks = 0; ks < 2; ++ks)
        a27[mm][ks] = *(const i32x4_t*)(myA + ((mm + 2) * 16 + rl) * 128
                                        + ((ks * 64 + g * 16) ^ colswz));
    stageB(t + 2, 0);
    asm volatile("s_waitcnt lgkmcnt(8)" ::: "memory");
    __builtin_amdgcn_s_barrier();
    asm volatile("s_waitcnt lgkmcnt(0)" ::: "memory");
    __builtin_amdgcn_sched_barrier(0);
    __builtin_amdgcn_s_setprio(1);
    quad(1, &a27[0]);
    __builtin_amdgcn_s_setprio(0);
    __builtin_amdgcn_s_barrier();

    // -------- P3: stage A0(t+2) --------
    stageA(t + 2, 0);
    __builtin_amdgcn_s_barrier();
    __builtin_amdgcn_s_setprio(1);
    quad(2, &a27[2]);
    __builtin_amdgcn_s_setprio(0);
    __builtin_amdgcn_s_barrier();

    // -------- P4: stage A1(t+2); counted vmcnt --------
    stageA(t + 2, 1);
    if (t < NT - 2) asm volatile("s_waitcnt vmcnt(6)" ::: "memory");
    else            asm volatile("s_waitcnt vmcnt(0)" ::: "memory");
    __builtin_amdgcn_s_barrier();
    __builtin_amdgcn_s_setprio(1);
    quad(3, &a27[4]);
    __builtin_amdgcn_s_setprio(0);
    __builtin_amdgcn_s_barrier();
  }

  // -------- epilogue --------
  const float invw = wsc[widx * 2 + 1];
  const int row0 = bm * 256 + wr * 128;
  const int col0 = bn * 256 + wc * 64;
  #pragma unroll
  for (int m = 0; m < 8; ++m) {
    #pragma unroll
    for (int r = 0; r < 4; ++r) {
      const int gb = row0 + m * 16 + g * 4 + r;
      const float fa = inv_sa[gb] * invw;
      #pragma unroll
      for (int n = 0; n < 4; ++n) {
        const int go = col0 + n * 16 + rl;
        const float v = (float)acc[m][n][r] * fa + bias[go];
        out[(size_t)gb * N + go] = TANH ? tanhf(v) : v;
      }
    }
  }
}

// ---------------- driver ----------------------------------------------------
extern "C" void kernel_launch(void* const* d_in, const int* in_sizes, int n_in,
                              void* d_out, int out_size, void* d_ws, size_t ws_size,
                              hipStream_t stream)
{
  const float* x  = (const float*)d_in[0];
  const float* w1 = (const float*)d_in[1]; const float* b1 = (const float*)d_in[2];
  const float* w2 = (const float*)d_in[3]; const float* b2 = (const float*)d_in[4];
  const float* w3 = (const float*)d_in[5]; const float* b3 = (const float*)d_in[6];
  const float* w4 = (const float*)d_in[7]; const float* b4 = (const float*)d_in[8];
  float* out = (float*)d_out;

  constexpr int B = 8192, DIN = 1024, H = 4096, DOUT = 1024;
  char* ws = (char*)d_ws;
  size_t off = 0;
  float*       hbuf = (float*)(ws + off);        off += (size_t)B * H * 4;
  signed char* xq   = (signed char*)(ws + off);  off += (size_t)B * H;
  signed char* wq   = (signed char*)(ws + off);  off += (size_t)H * H;
  float*       inv_sa = (float*)(ws + off);      off += (size_t)B * 4;
  double*      part = (double*)(ws + off);       off += 1024 * 8;
  float*       wsc  = (float*)(ws + off);        off += 64;

  absmean_part_k<<<1024, 256, 0, stream>>>(w1, H * DIN / 4, part);
  absmean_fin_k<<<1, 256, 0, stream>>>(part, 1024, (double)H * DIN, wsc, 0);
  absmean_part_k<<<1024, 256, 0, stream>>>(w2, H * H / 4, part);
  absmean_fin_k<<<1, 256, 0, stream>>>(part, 1024, (double)H * H, wsc, 1);
  absmean_part_k<<<1024, 256, 0, stream>>>(w3, H * H / 4, part);
  absmean_fin_k<<<1, 256, 0, stream>>>(part, 1024, (double)H * H, wsc, 2);
  absmean_part_k<<<1024, 256, 0, stream>>>(w4, DOUT * H / 4, part);
  absmean_fin_k<<<1, 256, 0, stream>>>(part, 1024, (double)DOUT * H, wsc, 3);

  // layer 1 (K=1024): 128^2 kernel
  act_quant_k<DIN><<<B, 256, 0, stream>>>(x, (unsigned int*)xq, inv_sa);
  quant_w_k<<<2048, 256, 0, stream>>>(w1, (unsigned int*)wq, wsc, 0, H * DIN / 4);
  gemm_bt<DIN, H, true><<<dim3(H / 128, B / 128), 256, 0, stream>>>(
      xq, wq, inv_sa, wsc, 0, b1, hbuf);

  // layer 2 (4096^2 x 8192): 256^2 8-phase
  act_quant_k<H><<<B, 256, 0, stream>>>(hbuf, (unsigned int*)xq, inv_sa);
  quant_w_k<<<2048, 256, 0, stream>>>(w2, (unsigned int*)wq, wsc, 1, H * H / 4);
  gemm8p<H, H, true><<<dim3(H / 256, B / 256), 512, 0, stream>>>(
      xq, wq, inv_sa, wsc, 1, b2, hbuf);

  // layer 3
  act_quant_k<H><<<B, 256, 0, stream>>>(hbuf, (unsigned int*)xq, inv_sa);
  quant_w_k<<<2048, 256, 0, stream>>>(w3, (unsigned int*)wq, wsc, 2, H * H / 4);
  gemm8p<H, H, true><<<dim3(H / 256, B / 256), 512, 0, stream>>>(
      xq, wq, inv_sa, wsc, 2, b3, hbuf);

  // layer 4 (N=1024): 128^2 kernel
  act_quant_k<H><<<B, 256, 0, stream>>>(hbuf, (unsigned int*)xq, inv_sa);
  quant_w_k<<<2048, 256, 0, stream>>>(w4, (unsigned int*)wq, wsc, 3, DOUT * H / 4);
  gemm_bt<H, DOUT, false><<<dim3(DOUT / 128, B / 128), 256, 0, stream>>>(
      xq, wq, inv_sa, wsc, 3, b4, out);
}

// Round 5
// 611.706 us; speedup vs baseline: 1.0474x; 1.0135x over previous
//
#include <hip/hip_runtime.h>
#include <hip/hip_bf16.h>

// BitNet 4-layer MLP forward, MI355X — round 5: re-time gemm8p register loads.
// Round 4 fixed bank conflicts (1.26e7 -> 0) but phases bunched 12/12/0/0
// ds_reads with full lgkm drains before MFMA -> no LDS/MFMA overlap.
// Now: fragments read one phase ahead (balanced 4/8/0/12-danglers), plain
// C++ loads so the compiler emits per-operand lgkmcnt; B + quad0-A fragments
// for tile t+1 read as danglers at P4 after vmcnt(6)+barrier.

typedef __attribute__((ext_vector_type(4))) int i32x4_t;

#define GLDS16(g, l) __builtin_amdgcn_global_load_lds( \
    (const __attribute__((address_space(1))) unsigned int*)(g), \
    (__attribute__((address_space(3))) unsigned int*)(l), 16, 0, 0)

static __device__ __forceinline__ unsigned char f2i8(float f) {
  return (unsigned char)(int)f;   // f already rint'ed and clipped
}

// ---------------- weight abs-mean (deterministic two-stage fp64) ------------
__global__ __launch_bounds__(256) void absmean_part_k(
    const float* __restrict__ W, int n4, double* __restrict__ part)
{
  double s = 0.0;
  const int stride = gridDim.x * 256;
  for (int i = blockIdx.x * 256 + threadIdx.x; i < n4; i += stride) {
    float4 v = ((const float4*)W)[i];
    s += (double)fabsf(v.x); s += (double)fabsf(v.y);
    s += (double)fabsf(v.z); s += (double)fabsf(v.w);
  }
  __shared__ double sd[256];
  sd[threadIdx.x] = s;
  __syncthreads();
  for (int st = 128; st > 0; st >>= 1) {
    if (threadIdx.x < st) sd[threadIdx.x] += sd[threadIdx.x + st];
    __syncthreads();
  }
  if (threadIdx.x == 0) part[blockIdx.x] = sd[0];
}

__global__ __launch_bounds__(256) void absmean_fin_k(
    const double* __restrict__ part, int nPart, double n,
    float* __restrict__ wsc, int widx)
{
  __shared__ double sd[256];
  double s = 0.0;
  for (int i = threadIdx.x; i < nPart; i += 256) s += part[i];
  sd[threadIdx.x] = s;
  __syncthreads();
  for (int st = 128; st > 0; st >>= 1) {
    if (threadIdx.x < st) sd[threadIdx.x] += sd[threadIdx.x + st];
    __syncthreads();
  }
  if (threadIdx.x == 0) {
    float mean = (float)(sd[0] / n);
    float scale = 1.f / fmaxf(mean, 1e-5f);
    wsc[widx * 2]     = scale;
    wsc[widx * 2 + 1] = 1.f / scale;
  }
}

// ---------------- weight ternary quantization to i8 {-1,0,1} ----------------
__global__ __launch_bounds__(256) void quant_w_k(
    const float* __restrict__ W, unsigned int* __restrict__ Wq,
    const float* __restrict__ wsc, int widx, int n4)
{
  const float s = wsc[widx * 2];
  const int stride = gridDim.x * 256;
  for (int i = blockIdx.x * 256 + threadIdx.x; i < n4; i += stride) {
    float4 v = ((const float4*)W)[i];
    unsigned int u =
        (unsigned int)f2i8(fminf(fmaxf(rintf(v.x * s), -1.f), 1.f)) |
        ((unsigned int)f2i8(fminf(fmaxf(rintf(v.y * s), -1.f), 1.f)) << 8) |
        ((unsigned int)f2i8(fminf(fmaxf(rintf(v.z * s), -1.f), 1.f)) << 16) |
        ((unsigned int)f2i8(fminf(fmaxf(rintf(v.w * s), -1.f), 1.f)) << 24);
    Wq[i] = u;
  }
}

// ---------------- per-row activation quantization to i8 ---------------------
template<int D>
__global__ __launch_bounds__(256) void act_quant_k(
    const float* __restrict__ X, unsigned int* __restrict__ Xq,
    float* __restrict__ inv_sa)
{
  constexpr int PER = D / 1024;
  const int row = blockIdx.x, tid = threadIdx.x;
  const float4* xr = (const float4*)(X + (size_t)row * D);
  float4 v[PER];
  float m = 0.f;
  #pragma unroll
  for (int i = 0; i < PER; ++i) {
    v[i] = xr[tid + 256 * i];
    m = fmaxf(m, fmaxf(fmaxf(fabsf(v[i].x), fabsf(v[i].y)),
                       fmaxf(fabsf(v[i].z), fabsf(v[i].w))));
  }
  #pragma unroll
  for (int off = 32; off >= 1; off >>= 1) m = fmaxf(m, __shfl_xor(m, off));
  __shared__ float wm[4];
  if ((tid & 63) == 0) wm[tid >> 6] = m;
  __syncthreads();
  m = fmaxf(fmaxf(wm[0], wm[1]), fmaxf(wm[2], wm[3]));
  const float s = 127.f / fmaxf(m, 1e-5f);
  if (tid == 0) inv_sa[row] = 1.f / s;
  unsigned int* oq = Xq + (size_t)row * (D / 4);
  #pragma unroll
  for (int i = 0; i < PER; ++i) {
    unsigned int u =
        (unsigned int)f2i8(fminf(fmaxf(rintf(v[i].x * s), -128.f), 127.f)) |
        ((unsigned int)f2i8(fminf(fmaxf(rintf(v[i].y * s), -128.f), 127.f)) << 8) |
        ((unsigned int)f2i8(fminf(fmaxf(rintf(v[i].z * s), -128.f), 127.f)) << 16) |
        ((unsigned int)f2i8(fminf(fmaxf(rintf(v[i].w * s), -128.f), 127.f)) << 24);
    oq[tid + 256 * i] = u;
  }
}

// ---------------- 128^2 2-phase i8 GEMM (proven; used for L1/L4) ------------
template<int K, int N, bool TANH>
__global__ __launch_bounds__(256) void gemm_bt(
    const signed char* __restrict__ A, const signed char* __restrict__ W,
    const float* __restrict__ inv_sa, const float* __restrict__ wsc, int widx,
    const float* __restrict__ bias, float* __restrict__ out)
{
  __shared__ __align__(16) signed char As[128 * 64];
  __shared__ __align__(16) signed char Bs[128 * 64];
  const int tid = threadIdx.x;
  const int wv = tid >> 6, ln = tid & 63;
  const int bm = blockIdx.y, bn = blockIdx.x;
  const int wr = wv >> 1, wc = wv & 1;
  const signed char* Ab = A + (size_t)bm * 128 * K;
  const signed char* Wb = W + (size_t)bn * 128 * K;
  i32x4_t acc[4][4];
  #pragma unroll
  for (int m = 0; m < 4; ++m)
    #pragma unroll
    for (int n = 0; n < 4; ++n) acc[m][n] = (i32x4_t){0, 0, 0, 0};

  for (int k0 = 0; k0 < K; k0 += 64) {
    #pragma unroll
    for (int l = 0; l < 2; ++l) {
      const int c = l * 256 + wv * 64 + ln;
      const int row = c >> 2;
      const int kc = (c & 3) * 16;
      GLDS16(Ab + (size_t)row * K + k0 + kc, As + (l * 256 + wv * 64) * 16);
      GLDS16(Wb + (size_t)row * K + k0 + kc, Bs + (l * 256 + wv * 64) * 16);
    }
    __syncthreads();
    i32x4_t aw[4], bw[4];
    #pragma unroll
    for (int m = 0; m < 4; ++m)
      aw[m] = *(const i32x4_t*)(As + (wr * 64 + m * 16 + (ln & 15)) * 64 + (ln >> 4) * 16);
    #pragma unroll
    for (int n = 0; n < 4; ++n)
      bw[n] = *(const i32x4_t*)(Bs + (wc * 64 + n * 16 + (ln & 15)) * 64 + (ln >> 4) * 16);
    #pragma unroll
    for (int m = 0; m < 4; ++m)
      #pragma unroll
      for (int n = 0; n < 4; ++n)
        acc[m][n] = __builtin_amdgcn_mfma_i32_16x16x64_i8(aw[m], bw[n], acc[m][n], 0, 0, 0);
    __syncthreads();
  }

  const float invw = wsc[widx * 2 + 1];
  #pragma unroll
  for (int m = 0; m < 4; ++m) {
    const int gb0 = bm * 128 + wr * 64 + m * 16 + ((ln >> 4) << 2);
    #pragma unroll
    for (int r = 0; r < 4; ++r) {
      const int gb = gb0 + r;
      const float fa = inv_sa[gb] * invw;
      #pragma unroll
      for (int n = 0; n < 4; ++n) {
        const int go = bn * 128 + wc * 64 + n * 16 + (ln & 15);
        const float v = (float)acc[m][n][r] * fa + bias[go];
        out[(size_t)gb * N + go] = TANH ? tanhf(v) : v;
      }
    }
  }
}

// ---------------- 256^2 8-phase i8 GEMM (T1..T5, pipelined reg-loads) -------
// BM=BN=256, BK=128 i8. 8 waves (2M x 4N), per-wave output 128x64.
// LDS 128KB: buf{0,1} x { A[2x16KB], B[2x16KB] }. 3-bit XOR swizzle (round 4).
// Per K-tile t: quad(q) consumes fragments read a phase earlier:
//   aq[0],bf   read at P4(t-1) as danglers (after vmcnt(6)+barrier)
//   P1: read aq[1];          stage B1(t+1); quad0
//   P2: read aq[2], aq[3];   stage B0(t+2); quad1
//   P3: lgkm(0) guard;       stage A0(t+2); quad2
//   P4: stage A1(t+2); vmcnt(6); barrier; quad3; read next bf,aq[0]
// All reads are plain C++ -> compiler emits per-operand lgkmcnt (no drains).
template<int K, int N, bool TANH>
__global__ __launch_bounds__(512, 2) void gemm8p(
    const signed char* __restrict__ A, const signed char* __restrict__ W,
    const float* __restrict__ inv_sa, const float* __restrict__ wsc, int widx,
    const float* __restrict__ bias, float* __restrict__ out)
{
  __shared__ __align__(16) signed char lds[131072];
  constexpr int NT = K / 128;
  const int tid = threadIdx.x;
  const int wv = tid >> 6, ln = tid & 63;
  const int wr = wv >> 2, wc = wv & 3;          // 2 x 4 wave grid
  const int g = ln >> 4, rl = ln & 15;
  const int colswz = (rl & 7) << 4;             // read-side 3-bit XOR

  // XCD-aware block swizzle (nwg % 8 == 0 for all our grids)
  const int nwg = gridDim.x * gridDim.y;
  int lbid = blockIdx.y * gridDim.x + blockIdx.x;
  lbid = (lbid & 7) * (nwg >> 3) + (lbid >> 3);
  const int bn = lbid % gridDim.x, bm = lbid / gridDim.x;

  const signed char* Abase = A + (size_t)bm * 256 * K;
  const signed char* Wbase = W + (size_t)bn * 256 * K;

  // staging: 2 x 16B chunks per thread per 16KB half-tile.
  // LDS chunk c (linear dest) sources global chunk c ^ ((c>>3)&7).
  const int c0 = tid, c1 = 512 + tid;
  const int r0 = c0 >> 3, k0c = ((c0 ^ (c0 >> 3)) & 7) * 16;
  const int r1 = c1 >> 3, k1c = ((c1 ^ (c1 >> 3)) & 7) * 16;

  auto stageA = [&](int tt, int h) {
    if (tt >= NT) return;
    signed char* d = lds + ((tt & 1) << 16) + h * 16384;
    const signed char* gsrc = Abase + (size_t)(h * 128) * K + (size_t)tt * 128;
    GLDS16(gsrc + (size_t)r0 * K + k0c, d + (c0 << 4));
    GLDS16(gsrc + (size_t)r1 * K + k1c, d + (c1 << 4));
  };
  auto stageB = [&](int tt, int h) {
    if (tt >= NT) return;
    signed char* d = lds + ((tt & 1) << 16) + 32768 + h * 16384;
    const signed char* gsrc = Wbase + (size_t)(h * 128) * K + (size_t)tt * 128;
    GLDS16(gsrc + (size_t)r0 * K + k0c, d + (c0 << 4));
    GLDS16(gsrc + (size_t)r1 * K + k1c, d + (c1 << 4));
  };

  i32x4_t acc[8][4];
  #pragma unroll
  for (int m = 0; m < 8; ++m)
    #pragma unroll
    for (int n = 0; n < 4; ++n) acc[m][n] = (i32x4_t){0, 0, 0, 0};

  i32x4_t bf[4][2];          // B fragments for current tile
  i32x4_t aq[4][2][2];       // A fragments, one quad ahead

  const int myAoff = wr * 16384;
  const int myBoff = 32768 + (wc >> 1) * 16384 + (wc & 1) * 8192;

  auto readA = [&](int q, const signed char* mA) {
    #pragma unroll
    for (int mm = 0; mm < 2; ++mm)
      #pragma unroll
      for (int ks = 0; ks < 2; ++ks)
        aq[q][mm][ks] = *(const i32x4_t*)(mA + ((q * 2 + mm) * 16 + rl) * 128
                                          + ((ks * 64 + g * 16) ^ colswz));
  };
  auto readB = [&](const signed char* mB) {
    #pragma unroll
    for (int n = 0; n < 4; ++n)
      #pragma unroll
      for (int ks = 0; ks < 2; ++ks)
        bf[n][ks] = *(const i32x4_t*)(mB + (n * 16 + rl) * 128
                                      + ((ks * 64 + g * 16) ^ colswz));
  };
  auto quad = [&](int q) {
    #pragma unroll
    for (int mm = 0; mm < 2; ++mm)
      #pragma unroll
      for (int n = 0; n < 4; ++n)
        #pragma unroll
        for (int ks = 0; ks < 2; ++ks)
          acc[q * 2 + mm][n] = __builtin_amdgcn_mfma_i32_16x16x64_i8(
              aq[q][mm][ks], bf[n][ks], acc[q * 2 + mm][n], 0, 0, 0);
  };

  // prologue: K-tile 0 fully + 3 halves of K-tile 1; then pre-read tile 0 frags
  stageA(0, 0); stageA(0, 1); stageB(0, 0); stageB(0, 1);
  stageB(1, 0); stageA(1, 0); stageA(1, 1);
  if (NT > 1) asm volatile("s_waitcnt vmcnt(6)" ::: "memory");
  else        asm volatile("s_waitcnt vmcnt(0)" ::: "memory");
  __builtin_amdgcn_s_barrier();
  readB(lds + myBoff);
  readA(0, lds + myAoff);

  for (int t = 0; t < NT; ++t) {
    const signed char* base = lds + ((t & 1) << 16);
    const signed char* myA = base + myAoff;

    // -------- P1: read aq[1]; stage B1(t+1); quad0 --------
    readA(1, myA);
    stageB(t + 1, 1);
    __builtin_amdgcn_s_barrier();
    __builtin_amdgcn_s_setprio(1);
    quad(0);
    __builtin_amdgcn_s_setprio(0);
    __builtin_amdgcn_s_barrier();

    // -------- P2: read aq[2], aq[3]; stage B0(t+2); quad1 --------
    readA(2, myA);
    readA(3, myA);
    stageB(t + 2, 0);
    __builtin_amdgcn_s_barrier();
    __builtin_amdgcn_s_setprio(1);
    quad(1);
    __builtin_amdgcn_s_setprio(0);
    __builtin_amdgcn_s_barrier();

    // -------- P3: guard aq reads complete, stage A0(t+2); quad2 --------
    asm volatile("s_waitcnt lgkmcnt(0)" ::: "memory");
    stageA(t + 2, 0);
    __builtin_amdgcn_s_barrier();
    __builtin_amdgcn_s_setprio(1);
    quad(2);
    __builtin_amdgcn_s_setprio(0);
    __builtin_amdgcn_s_barrier();

    // -------- P4: stage A1(t+2); counted vmcnt; quad3; next-tile danglers ---
    stageA(t + 2, 1);
    if (t < NT - 2) asm volatile("s_waitcnt vmcnt(6)" ::: "memory");
    else            asm volatile("s_waitcnt vmcnt(0)" ::: "memory");
    __builtin_amdgcn_s_barrier();
    __builtin_amdgcn_s_setprio(1);
    quad(3);
    __builtin_amdgcn_s_setprio(0);
    if (t + 1 < NT) {
      const signed char* nbase = lds + (((t + 1) & 1) << 16);
      readB(nbase + myBoff);
      readA(0, nbase + myAoff);
    }
    __builtin_amdgcn_s_barrier();
  }

  // -------- epilogue --------
  const float invw = wsc[widx * 2 + 1];
  const int row0 = bm * 256 + wr * 128;
  const int col0 = bn * 256 + wc * 64;
  #pragma unroll
  for (int m = 0; m < 8; ++m) {
    #pragma unroll
    for (int r = 0; r < 4; ++r) {
      const int gb = row0 + m * 16 + g * 4 + r;
      const float fa = inv_sa[gb] * invw;
      #pragma unroll
      for (int n = 0; n < 4; ++n) {
        const int go = col0 + n * 16 + rl;
        const float v = (float)acc[m][n][r] * fa + bias[go];
        out[(size_t)gb * N + go] = TANH ? tanhf(v) : v;
      }
    }
  }
}

// ---------------- driver ----------------------------------------------------
extern "C" void kernel_launch(void* const* d_in, const int* in_sizes, int n_in,
                              void* d_out, int out_size, void* d_ws, size_t ws_size,
                              hipStream_t stream)
{
  const float* x  = (const float*)d_in[0];
  const float* w1 = (const float*)d_in[1]; const float* b1 = (const float*)d_in[2];
  const float* w2 = (const float*)d_in[3]; const float* b2 = (const float*)d_in[4];
  const float* w3 = (const float*)d_in[5]; const float* b3 = (const float*)d_in[6];
  const float* w4 = (const float*)d_in[7]; const float* b4 = (const float*)d_in[8];
  float* out = (float*)d_out;

  constexpr int B = 8192, DIN = 1024, H = 4096, DOUT = 1024;
  char* ws = (char*)d_ws;
  size_t off = 0;
  float*       hbuf = (float*)(ws + off);        off += (size_t)B * H * 4;
  signed char* xq   = (signed char*)(ws + off);  off += (size_t)B * H;
  signed char* wq   = (signed char*)(ws + off);  off += (size_t)H * H;
  float*       inv_sa = (float*)(ws + off);      off += (size_t)B * 4;
  double*      part = (double*)(ws + off);       off += 1024 * 8;
  float*       wsc  = (float*)(ws + off);        off += 64;

  absmean_part_k<<<1024, 256, 0, stream>>>(w1, H * DIN / 4, part);
  absmean_fin_k<<<1, 256, 0, stream>>>(part, 1024, (double)H * DIN, wsc, 0);
  absmean_part_k<<<1024, 256, 0, stream>>>(w2, H * H / 4, part);
  absmean_fin_k<<<1, 256, 0, stream>>>(part, 1024, (double)H * H, wsc, 1);
  absmean_part_k<<<1024, 256, 0, stream>>>(w3, H * H / 4, part);
  absmean_fin_k<<<1, 256, 0, stream>>>(part, 1024, (double)H * H, wsc, 2);
  absmean_part_k<<<1024, 256, 0, stream>>>(w4, DOUT * H / 4, part);
  absmean_fin_k<<<1, 256, 0, stream>>>(part, 1024, (double)DOUT * H, wsc, 3);

  // layer 1 (K=1024): 128^2 kernel
  act_quant_k<DIN><<<B, 256, 0, stream>>>(x, (unsigned int*)xq, inv_sa);
  quant_w_k<<<2048, 256, 0, stream>>>(w1, (unsigned int*)wq, wsc, 0, H * DIN / 4);
  gemm_bt<DIN, H, true><<<dim3(H / 128, B / 128), 256, 0, stream>>>(
      xq, wq, inv_sa, wsc, 0, b1, hbuf);

  // layer 2 (4096^2 x 8192): 256^2 8-phase
  act_quant_k<H><<<B, 256, 0, stream>>>(hbuf, (unsigned int*)xq, inv_sa);
  quant_w_k<<<2048, 256, 0, stream>>>(w2, (unsigned int*)wq, wsc, 1, H * H / 4);
  gemm8p<H, H, true><<<dim3(H / 256, B / 256), 512, 0, stream>>>(
      xq, wq, inv_sa, wsc, 1, b2, hbuf);

  // layer 3
  act_quant_k<H><<<B, 256, 0, stream>>>(hbuf, (unsigned int*)xq, inv_sa);
  quant_w_k<<<2048, 256, 0, stream>>>(w3, (unsigned int*)wq, wsc, 2, H * H / 4);
  gemm8p<H, H, true><<<dim3(H / 256, B / 256), 512, 0, stream>>>(
      xq, wq, inv_sa, wsc, 2, b3, hbuf);

  // layer 4 (N=1024): 128^2 kernel
  act_quant_k<H><<<B, 256, 0, stream>>>(hbuf, (unsigned int*)xq, inv_sa);
  quant_w_k<<<2048, 256, 0, stream>>>(w4, (unsigned int*)wq, wsc, 3, DOUT * H / 4);
  gemm_bt<H, DOUT, false><<<dim3(DOUT / 128, B / 128), 256, 0, stream>>>(
      xq, wq, inv_sa, wsc, 3, b4, out);
}